// Round 4
// baseline (15484.821 us; speedup 1.0000x reference)
//
#include <hip/hip_runtime.h>
#include <math.h>

#define T_STEPS 4096
#define HID     2048
#define MOD     256
#define INSZ    1024

#define NBLK 32          // blocks in recurrence kernel
#define NTHR 512         // threads per block (8 waves = 2 waves/SIMD)
#define RPM  8           // rest rows per module owned by each block
#define NCE  8           // C entries owned by each block (== waves)

// ---------------------------------------------------------------------------
// Agent-scope (device-coherent) helpers: serviced at the LLC, bypassing the
// non-coherent per-XCD L2s. Packets are self-validating (tag<<32 | fp32 bits)
// so relaxed ordering is sufficient.
// ---------------------------------------------------------------------------
static __device__ __forceinline__ unsigned long long agent_load_u64(
        const unsigned long long* p) {
    return __hip_atomic_load((unsigned long long*)p, __ATOMIC_RELAXED,
                             __HIP_MEMORY_SCOPE_AGENT);
}
static __device__ __forceinline__ void agent_store_u64(
        unsigned long long* p, unsigned long long v) {
    __hip_atomic_store(p, v, __ATOMIC_RELAXED, __HIP_MEMORY_SCOPE_AGENT);
}

// ---------------------------------------------------------------------------
// Kernel 1 (unchanged): U = x @ W_ih^T + (b_ih + b_hh) into out[t, i].
// ---------------------------------------------------------------------------
#define BM 128
#define BN 128
#define BK 8

__global__ __launch_bounds__(256) void gemm_u(
    const float* __restrict__ x, const float* __restrict__ Wih,
    const float* __restrict__ bih, const float* __restrict__ bhh,
    float* __restrict__ out)
{
    __shared__ float As[BK][BM];
    __shared__ float Bs[BK][BN];

    const int tid = threadIdx.x;
    const int t0 = blockIdx.y * BM;
    const int i0 = blockIdx.x * BN;
    const int tx = tid & 15;
    const int ty = tid >> 4;
    const int arow = tid >> 1;
    const int acol = (tid & 1) * 4;

    float acc[8][8];
#pragma unroll
    for (int a = 0; a < 8; ++a)
#pragma unroll
        for (int b = 0; b < 8; ++b) acc[a][b] = 0.0f;

    for (int k0 = 0; k0 < INSZ; k0 += BK) {
        float4 av = *(const float4*)(x   + (size_t)(t0 + arow) * INSZ + k0 + acol);
        float4 bv = *(const float4*)(Wih + (size_t)(i0 + arow) * INSZ + k0 + acol);
        __syncthreads();
        As[acol + 0][arow] = av.x; As[acol + 1][arow] = av.y;
        As[acol + 2][arow] = av.z; As[acol + 3][arow] = av.w;
        Bs[acol + 0][arow] = bv.x; Bs[acol + 1][arow] = bv.y;
        Bs[acol + 2][arow] = bv.z; Bs[acol + 3][arow] = bv.w;
        __syncthreads();
#pragma unroll
        for (int kk = 0; kk < BK; ++kk) {
            float a[8], b[8];
            *(float4*)&a[0] = *(const float4*)&As[kk][ty * 8];
            *(float4*)&a[4] = *(const float4*)&As[kk][ty * 8 + 4];
            *(float4*)&b[0] = *(const float4*)&Bs[kk][tx * 8];
            *(float4*)&b[4] = *(const float4*)&Bs[kk][tx * 8 + 4];
#pragma unroll
            for (int ri = 0; ri < 8; ++ri)
#pragma unroll
                for (int ci = 0; ci < 8; ++ci)
                    acc[ri][ci] = fmaf(a[ri], b[ci], acc[ri][ci]);
        }
    }

    float bias[8];
#pragma unroll
    for (int ci = 0; ci < 8; ++ci) {
        int i = i0 + tx * 8 + ci;
        bias[ci] = bih[i] + bhh[i];
    }
#pragma unroll
    for (int ri = 0; ri < 8; ++ri) {
        int t = t0 + ty * 8 + ri;
#pragma unroll
        for (int ci = 0; ci < 8; ++ci) {
            int i = i0 + tx * 8 + ci;
            out[(size_t)t * HID + i] = acc[ri][ci] + bias[ci];
        }
    }
}

// ---------------------------------------------------------------------------
// Kernel 2: replicated-module-0 recurrence. 32 blocks x 512 threads.
//
// vs r3 (structure otherwise identical, correctness-equivalent):
//  (a) dC weights W_hh[8b..8b+8, 256:2048] preloaded to LDS (56 KB) once:
//      the per-even-step dC is pure LDS+FMA instead of L2-latency loads.
//  (b) odd steps poll comm_c[myrow] PER-THREAD and use the value directly:
//      removes the lds_C staging round-trip and 2 barriers per odd step.
//      The polled value is stashed to lds_C (by the c16<8 twin) for the next
//      even step's module-0 term (vintage t-2) and as the dC base.
//  (c) the C poll load is issued at the even-step tail (right after the C
//      publish), so the LLC round trip overlaps barrier + odd early phase +
//      the W00 MAC.
//
// Skew bound (unchanged): odd-step C-poll gates every block on ALL C(t-1)
// entries (each block owns 8), so no block can be >2 steps ahead of any
// other => single-slot packets and the 3-deep out-row ring remain safe.
// ---------------------------------------------------------------------------
__global__ __launch_bounds__(NTHR)
__attribute__((amdgpu_waves_per_eu(2, 2)))
void cwrnn_rec(
    float* __restrict__ out, const float* __restrict__ Whh,
    unsigned long long* __restrict__ comm)
{
    const int tid   = threadIdx.x;
    const int b     = blockIdx.x;        // 0..31
    const int lane  = tid & 63;
    const int wave  = tid >> 6;          // 0..7
    const int r8    = tid >> 4;          // row group: rows 8*r8..8*r8+7
    const int c16   = tid & 15;          // col group: cols 16*c16..16*c16+15
    const int rsel  = c16 & 7;
    const int myrow = 8 * r8 + rsel;     // row this thread finalizes (c16<8)

    unsigned long long* comm_h = comm;            // [7*256] rest-row packets
    unsigned long long* comm_c = comm + 7 * MOD;  // [256]   C packets

    __shared__ __align__(16) float lds_h[HID];       // replicated full h
    __shared__ __align__(16) float h0p[320];         // padded h0: word = e + (e>>4)*4
    __shared__ __align__(16) float lds_C[MOD];       // C stash (vintage t-2 at even t)
    __shared__ __align__(16) float lds_delta[7 * MOD];
    __shared__ __align__(16) float lds_u0[MOD];      // U0[t] (prefetched)
    __shared__ __align__(16) float lds_ur[56];       // U[t] for owned rest rows
    __shared__ __align__(16) float lds_ring[3][64];  // delayed out slice
    __shared__ __align__(16) float lds_wc[NCE][7 * MOD];  // dC weights (56 KB)

    // ---- W00 fragment in registers/AGPRs: rows 8r8..+7, cols 16c16..+15
    float4 w00[8][4];
#pragma unroll
    for (int rr = 0; rr < 8; ++rr) {
        const float* wr = Whh + (size_t)(8 * r8 + rr) * HID + 16 * c16;
#pragma unroll
        for (int i = 0; i < 4; ++i) w00[rr][i] = *(const float4*)(wr + 4 * i);
    }

    // ---- preload dC weights: rows 8b..8b+7, cols 256..2047 -> LDS
#pragma unroll
    for (int r = 0; r < NCE; ++r) {
        if (tid < 448)
            *(float4*)&lds_wc[r][4 * tid] =
                *(const float4*)(Whh + (size_t)(NCE * b + r) * HID + MOD + 4 * tid);
    }

    // ---- zero init (h(0) = 0, C(0) = 0)
    for (int i = tid; i < HID; i += NTHR) lds_h[i] = 0.f;
    if (tid < 320) h0p[tid] = 0.f;
    if (tid < MOD) lds_C[tid] = 0.f;
    if (tid < 56)  lds_ur[tid] = 0.f;
    if (tid < 192) (&lds_ring[0][0])[tid] = 0.f;

    {   // preload U(1) = gemm row 0, cols [0,256)
        float4 u4 = make_float4(0.f, 0.f, 0.f, 0.f);
        if (tid < 64) u4 = *(const float4*)(out + 4 * tid);
        __syncthreads();
        if (tid < 64) *(float4*)(lds_u0 + 4 * tid) = u4;
        __syncthreads();
    }

    // C packet carried across iterations; tag 0 (memset) is valid for t=1.
    unsigned long long cp = 0;

    for (int t = 1; t <= T_STEPS; ++t) {
        const bool ev = (t & 1) == 0;
        const int ctz = __builtin_ctz(t);
        const int j   = ev ? (ctz < 7 ? ctz : 7) : 0;  // active rest modules 1..j
        const unsigned long long tagbits =
            ((unsigned long long)(unsigned)t) << 32;

        // ---------- early phase: U value, delayed emission, U prefetch issue
        const float uval = lds_u0[myrow];
        if (t >= 3 && tid < 16) {   // emit out row t-3 = h(t-2), slot (t+1)%3
            float4 e4 = *(const float4*)(&lds_ring[(t + 1) % 3][4 * tid]);
            *(float4*)(out + (size_t)(t - 3) * HID + 64 * b + 4 * tid) = e4;
        }
        float4 pf0 = make_float4(0.f, 0.f, 0.f, 0.f);
        float4 pfr = make_float4(0.f, 0.f, 0.f, 0.f);
        if (t < T_STEPS) {
            if (tid < 64)   // U0 for step t+1 (gemm row t)
                pf0 = *(const float4*)(out + (size_t)t * HID + 4 * tid);
            if (!ev && tid >= 64 && tid < 78) {  // rest-U for even step t+1
                const int idx = tid - 64, mm = idx >> 1, dd = idx & 1;
                pfr = *(const float4*)(out + (size_t)t * HID
                                       + (mm + 1) * MOD + RPM * b + 4 * dd);
            }
        }

        // ---------- even: owned rest rows (full 2048-dot) + publish
        if (ev) {
            for (int ridx = wave; ridx < RPM * j; ridx += 8) {
                const int m = 1 + (ridx >> 3);
                const int e = ridx & 7;
                const float* wrow = Whh + (size_t)(m * MOD + RPM * b + e) * HID;
                float4 wv[8];
#pragma unroll
                for (int k = 0; k < 8; ++k)
                    wv[k] = *(const float4*)(wrow + 4 * lane + 256 * k);
                float sx = 0.f, sy = 0.f, sz = 0.f, sw = 0.f;
#pragma unroll
                for (int k = 0; k < 8; ++k) {
                    const float4 hv = *(const float4*)(lds_h + 4 * lane + 256 * k);
                    sx = fmaf(wv[k].x, hv.x, sx);
                    sy = fmaf(wv[k].y, hv.y, sy);
                    sz = fmaf(wv[k].z, hv.z, sz);
                    sw = fmaf(wv[k].w, hv.w, sw);
                }
                float acc = (sx + sy) + (sz + sw);
#pragma unroll
                for (int off = 32; off; off >>= 1)
                    acc += __shfl_xor(acc, off, 64);
                if (lane == 0) {
                    const float hv = tanhf(lds_ur[(m - 1) * 8 + e] + acc);
                    agent_store_u64(comm_h + (m - 1) * MOD + RPM * b + e,
                        tagbits | (unsigned long long)__float_as_uint(hv));
                }
            }
        }

        // ---------- even: issue h-packet poll loads (hidden under W00 MAC)
        const int nslot = j * MOD;
        unsigned long long hp0 = 0, hp1 = 0, hp2 = 0, hp3 = 0;
        const bool hw0 = ev && (tid < nslot);
        const bool hw1 = ev && (tid + 512 < nslot);
        const bool hw2 = ev && (tid + 1024 < nslot);
        const bool hw3 = ev && (tid + 1536 < nslot);
        if (ev) {
            if (hw0) hp0 = agent_load_u64(comm_h + tid);
            if (hw1) hp1 = agent_load_u64(comm_h + tid + 512);
            if (hw2) hp2 = agent_load_u64(comm_h + tid + 1024);
            if (hw3) hp3 = agent_load_u64(comm_h + tid + 1536);
        }

        // ---------- module-0 MAC (every step, fully local): W00 . h0(t-1)
        float a[8];
#pragma unroll
        for (int rr = 0; rr < 8; ++rr) a[rr] = 0.f;
#pragma unroll
        for (int i = 0; i < 4; ++i) {
            const float4 hv = *(const float4*)(h0p + 20 * c16 + 4 * i);
#pragma unroll
            for (int rr = 0; rr < 8; ++rr) {
                a[rr] = fmaf(w00[rr][i].x, hv.x, a[rr]);
                a[rr] = fmaf(w00[rr][i].y, hv.y, a[rr]);
                a[rr] = fmaf(w00[rr][i].z, hv.z, a[rr]);
                a[rr] = fmaf(w00[rr][i].w, hv.w, a[rr]);
            }
        }
#pragma unroll
        for (int off = 1; off <= 8; off <<= 1) {
#pragma unroll
            for (int rr = 0; rr < 8; ++rr)
                a[rr] += __shfl_xor(a[rr], off, 64);
        }
        float pre = a[0];                    // static-index select (rule #20)
#pragma unroll
        for (int rr = 1; rr < 8; ++rr) pre = (rsel == rr) ? a[rr] : pre;

        if (!ev) {
            // ---- odd: finish per-thread C poll (tag t-1; load was issued at
            //      the previous even-step tail; t=1 passes on memset tag 0)
            {
                const unsigned need = (unsigned)(t - 1);
                while ((unsigned)(cp >> 32) < need)
                    cp = agent_load_u64(comm_c + myrow);
            }
            const float cval = __uint_as_float((unsigned)cp);
            const float hv_new = tanhf(uval + cval + pre);
            __syncthreads();                                   // A (h0p/u0 reads done)
            if (c16 < 8) {
                lds_h[myrow] = hv_new;
                h0p[myrow + (myrow >> 4) * 4] = hv_new;
                lds_C[myrow] = cval;          // stash C(t-1) for even t+1
                if (b < 4 && (myrow >> 6) == b)
                    lds_ring[t % 3][myrow & 63] = hv_new;
            }
            if (b >= 4 && tid < 16)   // slice unchanged at odd steps: carry
                *(float4*)(&lds_ring[t % 3][4 * tid]) =
                    *(const float4*)(&lds_ring[(t + 2) % 3][4 * tid]);
            if (t < T_STEPS) {
                if (tid < 64) *(float4*)(lds_u0 + 4 * tid) = pf0;
                if (tid >= 64 && tid < 78) {
                    const int idx = tid - 64;
                    *(float4*)(lds_ur + (idx >> 1) * 8 + 4 * (idx & 1)) = pfr;
                }
            }
            __syncthreads();                                   // B (end)
        } else {
            // ---- even: finish module-0 with stashed C (vintage t-2)
            const float hv_new = tanhf(uval + lds_C[myrow] + pre);
            // ---- finish h-packet poll (tag t), register-only retry
            {
                const unsigned need = (unsigned)t;
                for (;;) {
                    bool ok = (!hw0 || (unsigned)(hp0 >> 32) >= need)
                           && (!hw1 || (unsigned)(hp1 >> 32) >= need)
                           && (!hw2 || (unsigned)(hp2 >> 32) >= need)
                           && (!hw3 || (unsigned)(hp3 >> 32) >= need);
                    if (ok) break;
                    if (hw0) hp0 = agent_load_u64(comm_h + tid);
                    if (hw1) hp1 = agent_load_u64(comm_h + tid + 512);
                    if (hw2) hp2 = agent_load_u64(comm_h + tid + 1024);
                    if (hw3) hp3 = agent_load_u64(comm_h + tid + 1536);
                }
            }
            __syncthreads();                                   // A (all lds_h reads done)
            if (c16 < 8) {
                lds_h[myrow] = hv_new;
                h0p[myrow + (myrow >> 4) * 4] = hv_new;
                if (b < 4 && (myrow >> 6) == b)
                    lds_ring[t % 3][myrow & 63] = hv_new;
            }
            {   // commit polled rest-h values, form deltas, update ring slice
                const int base = 64 * b - MOD;   // slice slot base (b>=4)
                if (hw0) {
                    const float v = __uint_as_float((unsigned)hp0);
                    const int s = tid;
                    lds_delta[s] = v - lds_h[MOD + s];
                    lds_h[MOD + s] = v;
                    if (b >= 4 && s >= base && s < base + 64)
                        lds_ring[t % 3][s - base] = v;
                }
                if (hw1) {
                    const float v = __uint_as_float((unsigned)hp1);
                    const int s = tid + 512;
                    lds_delta[s] = v - lds_h[MOD + s];
                    lds_h[MOD + s] = v;
                    if (b >= 4 && s >= base && s < base + 64)
                        lds_ring[t % 3][s - base] = v;
                }
                if (hw2) {
                    const float v = __uint_as_float((unsigned)hp2);
                    const int s = tid + 1024;
                    lds_delta[s] = v - lds_h[MOD + s];
                    lds_h[MOD + s] = v;
                    if (b >= 4 && s >= base && s < base + 64)
                        lds_ring[t % 3][s - base] = v;
                }
                if (hw3) {
                    const float v = __uint_as_float((unsigned)hp3);
                    const int s = tid + 1536;
                    lds_delta[s] = v - lds_h[MOD + s];
                    lds_h[MOD + s] = v;
                    if (b >= 4 && s >= base && s < base + 64)
                        lds_ring[t % 3][s - base] = v;
                }
            }
            if (b >= 4 && (b >> 2) > j && tid < 16)  // slice module inactive
                *(float4*)(&lds_ring[t % 3][4 * tid]) =
                    *(const float4*)(&lds_ring[(t + 2) % 3][4 * tid]);
            if (t < T_STEPS && tid < 64)
                *(float4*)(lds_u0 + 4 * tid) = pf0;
            __syncthreads();                                   // B
            // ---- owned dC entry (wave e) from LDS weights + publish (tag t).
            // Safe without a trailing barrier: lds_C[gi] is re-written only at
            // the next odd step, gated through the comm_c packet itself.
            {
                const float* wc = &lds_wc[wave][0];
                float acc = 0.f;
                for (int k0 = 0; k0 < nslot; k0 += 256) {
                    acc = fmaf(wc[k0 + lane],       lds_delta[k0 + lane],       acc);
                    acc = fmaf(wc[k0 + lane + 64],  lds_delta[k0 + lane + 64],  acc);
                    acc = fmaf(wc[k0 + lane + 128], lds_delta[k0 + lane + 128], acc);
                    acc = fmaf(wc[k0 + lane + 192], lds_delta[k0 + lane + 192], acc);
                }
#pragma unroll
                for (int off = 32; off; off >>= 1)
                    acc += __shfl_xor(acc, off, 64);
                if (lane == 0) {
                    const int gi = NCE * b + wave;
                    const float cn = lds_C[gi] + acc;
                    agent_store_u64(comm_c + gi,
                        tagbits | (unsigned long long)__float_as_uint(cn));
                }
            }
            // ---- issue next odd step's C poll now: RT hides under the
            //      barrier-free tail + next step's early phase + W00 MAC.
            cp = agent_load_u64(comm_c + myrow);
        }
    }

    // ---- flush the last two delayed rows: h(T-1) -> row T-2, h(T) -> row T-1
    __syncthreads();
    if (tid < 16) {
        *(float4*)(out + (size_t)(T_STEPS - 2) * HID + 64 * b + 4 * tid) =
            *(const float4*)(&lds_ring[(T_STEPS - 1) % 3][4 * tid]);
        *(float4*)(out + (size_t)(T_STEPS - 1) * HID + 64 * b + 4 * tid) =
            *(const float4*)(&lds_ring[T_STEPS % 3][4 * tid]);
    }
}

// ---------------------------------------------------------------------------
extern "C" void kernel_launch(void* const* d_in, const int* in_sizes, int n_in,
                              void* d_out, int out_size, void* d_ws, size_t ws_size,
                              hipStream_t stream) {
    const float* x   = (const float*)d_in[0];
    const float* Wih = (const float*)d_in[1];
    const float* Whh = (const float*)d_in[2];
    const float* bih = (const float*)d_in[3];
    const float* bhh = (const float*)d_in[4];
    float* out = (float*)d_out;
    unsigned long long* comm = (unsigned long long*)d_ws;

    // packet tags must start at 0 (t runs 1..4096): (1792 + 256) x 8B = 16 KB
    hipMemsetAsync(d_ws, 0, (7 * MOD + MOD) * sizeof(unsigned long long), stream);

    dim3 g1(HID / BN, T_STEPS / BM);        // (16, 32)
    gemm_u<<<g1, 256, 0, stream>>>(x, Wih, bih, bhh, out);
    cwrnn_rec<<<NBLK, NTHR, 0, stream>>>(out, Whh, comm);
}